// Round 1
// baseline (121.644 us; speedup 1.0000x reference)
//
#include <hip/hip_runtime.h>

// Problem constants (fixed by the reference)
#define BATCH 32
#define NN    128                 // nodes
#define NIN   128                 // node features
#define NHID  256                 // hidden
#define NOUT  128                 // output features
#define ROWS  (BATCH * NN)        // 4096 flattened (b,n) rows

// ---------------------------------------------------------------------------
// K1: S[row,c] = x[row,:] @ W1[0:128, c]
//     R[row,c] = x[row,:] @ W1[128:256, c] + b1[c]
// 8 rows per block, 256 threads = one thread per hidden channel c.
// ---------------------------------------------------------------------------
__global__ __launch_bounds__(256) void k1_sr(
    const float* __restrict__ x, const float* __restrict__ W1,
    const float* __restrict__ b1, float* __restrict__ S, float* __restrict__ R)
{
    __shared__ float xr[8][128];          // 4 KB
    const int row0 = blockIdx.x * 8;
    const int t = threadIdx.x;
    for (int idx = t; idx < 8 * 128; idx += 256)
        xr[idx >> 7][idx & 127] = x[(size_t)row0 * NIN + idx];
    __syncthreads();

    const int c = t;                      // 0..255
    float accs[8], accr[8];
#pragma unroll
    for (int r = 0; r < 8; ++r) { accs[r] = 0.f; accr[r] = 0.f; }

    for (int k = 0; k < NIN; k += 4) {
        float wa[4], wb[4];
#pragma unroll
        for (int kk = 0; kk < 4; ++kk) {
            wa[kk] = W1[(size_t)(k + kk) * NHID + c];          // sender half
            wb[kk] = W1[(size_t)(NIN + k + kk) * NHID + c];    // receiver half
        }
#pragma unroll
        for (int r = 0; r < 8; ++r) {
            const float4 xv = *(const float4*)(&xr[r][k]);     // wave-uniform LDS broadcast
            accs[r] = fmaf(xv.w, wa[3], fmaf(xv.z, wa[2], fmaf(xv.y, wa[1], fmaf(xv.x, wa[0], accs[r]))));
            accr[r] = fmaf(xv.w, wb[3], fmaf(xv.z, wb[2], fmaf(xv.y, wb[1], fmaf(xv.x, wb[0], accr[r]))));
        }
    }
    const float bias = b1[c];
#pragma unroll
    for (int r = 0; r < 8; ++r) {
        S[(size_t)(row0 + r) * NHID + c] = accs[r];
        R[(size_t)(row0 + r) * NHID + c] = accr[r] + bias;
    }
}

// ---------------------------------------------------------------------------
// K2: G[b,n,c] = sum_{i=0..127} relu(S[b,i,c] + R[b,n,c]) - relu(S[b,n,c]+R[b,n,c])
// Block = (b, n-tile of 32, c-chunk of 64). 32*4*4 = 512 blocks, 256 threads.
// Thread: (c_local = t&63, n-group = t>>6 of 8 receivers).
// ---------------------------------------------------------------------------
__global__ __launch_bounds__(256) void k2_g(
    const float* __restrict__ S, const float* __restrict__ R, float* __restrict__ G)
{
    const int blk = blockIdx.x;
    const int b   = blk >> 4;             // 0..31
    const int nt  = (blk >> 2) & 3;       // n-tile 0..3 (32 receivers each)
    const int cc  = blk & 3;              // c-chunk 0..3 (64 channels each)
    const int c0  = cc * 64;

    __shared__ float s_lds[128][64];      // 32 KB: S[b, all senders, c-chunk]
    const int t  = threadIdx.x;
    const int cl = t & 63;
    const int ng = t >> 6;                // 0..3

    for (int idx = t; idx < 128 * 64; idx += 256) {
        const int i = idx >> 6, c = idx & 63;
        s_lds[i][c] = S[((size_t)(b * NN + i)) * NHID + c0 + c];
    }
    __syncthreads();

    const int n0 = nt * 32 + ng * 8;      // first of this thread's 8 receivers
    float rv[8], acc[8];
#pragma unroll
    for (int q = 0; q < 8; ++q) {
        rv[q]  = R[((size_t)(b * NN + n0 + q)) * NHID + c0 + cl];
        acc[q] = 0.f;
    }

    for (int i = 0; i < 128; ++i) {
        const float s = s_lds[i][cl];     // 64 lanes -> 64 consecutive floats: 2-way (free)
#pragma unroll
        for (int q = 0; q < 8; ++q)
            acc[q] += fmaxf(s + rv[q], 0.f);
    }

#pragma unroll
    for (int q = 0; q < 8; ++q) {
        const float self = fmaxf(s_lds[n0 + q][cl] + rv[q], 0.f);
        G[((size_t)(b * NN + n0 + q)) * NHID + c0 + cl] = acc[q] - self;
    }
}

// ---------------------------------------------------------------------------
// K3: out[row, c] = (G[row,:] @ W2[:, c] + 127*b2[c]) / (127 + 1e-6)
// 16 rows per block, 256 threads: c = t&127, row-half = t>>7 (8 rows each).
// ---------------------------------------------------------------------------
__global__ __launch_bounds__(256) void k3_out(
    const float* __restrict__ G, const float* __restrict__ W2,
    const float* __restrict__ b2, float* __restrict__ out)
{
    __shared__ float g[16][256];          // 16 KB
    const int row0 = blockIdx.x * 16;
    const int t = threadIdx.x;
    for (int idx = t; idx < 16 * 256; idx += 256)
        g[idx >> 8][idx & 255] = G[(size_t)row0 * NHID + idx];
    __syncthreads();

    const int c  = t & 127;
    const int rh = t >> 7;                // 0 or 1
    float acc[8];
#pragma unroll
    for (int r = 0; r < 8; ++r) acc[r] = 0.f;

    for (int k = 0; k < NHID; k += 4) {
        float w[4];
#pragma unroll
        for (int kk = 0; kk < 4; ++kk)
            w[kk] = W2[(size_t)(k + kk) * NOUT + c];
#pragma unroll
        for (int r = 0; r < 8; ++r) {
            const float4 gv = *(const float4*)(&g[rh * 8 + r][k]);
            acc[r] = fmaf(gv.w, w[3], fmaf(gv.z, w[2], fmaf(gv.y, w[1], fmaf(gv.x, w[0], acc[r]))));
        }
    }
    const float inv  = 1.0f / (127.0f + 1e-6f);
    const float bias = 127.0f * b2[c];
#pragma unroll
    for (int r = 0; r < 8; ++r)
        out[(size_t)(row0 + rh * 8 + r) * NOUT + c] = (acc[r] + bias) * inv;
}

// ---------------------------------------------------------------------------
extern "C" void kernel_launch(void* const* d_in, const int* in_sizes, int n_in,
                              void* d_out, int out_size, void* d_ws, size_t ws_size,
                              hipStream_t stream)
{
    const float* x  = (const float*)d_in[0];
    // d_in[1] rel_type, d_in[2] rel_rec, d_in[3] rel_send: structurally fixed, unused
    const float* W1 = (const float*)d_in[4];
    const float* b1 = (const float*)d_in[5];
    const float* W2 = (const float*)d_in[6];
    const float* b2 = (const float*)d_in[7];
    float* out = (float*)d_out;

    float* S = (float*)d_ws;                       // 4096*256 f32 = 4 MB
    float* R = S + (size_t)ROWS * NHID;            // 4 MB
    float* G = R + (size_t)ROWS * NHID;            // 4 MB  (total 12 MB of ws)

    k1_sr <<<ROWS / 8,        256, 0, stream>>>(x, W1, b1, S, R);
    k2_g  <<<BATCH * 4 * 4,   256, 0, stream>>>(S, R, G);
    k3_out<<<ROWS / 16,       256, 0, stream>>>(G, W2, b2, out);
}